// Round 5
// baseline (2894.572 us; speedup 1.0000x reference)
//
#include <hip/hip_runtime.h>
#include <hip/hip_bf16.h>

#define B_ 16
#define S_ 512
#define H_ 512
#define V_ 10000
#define G_ 2048
#define M_ (B_*S_)   // 8192 tokens

typedef short bf16x8 __attribute__((ext_vector_type(8)));
typedef float f32x4 __attribute__((ext_vector_type(4)));
typedef _Float16 f16x8 __attribute__((ext_vector_type(8)));
typedef unsigned int u32x4 __attribute__((ext_vector_type(4)));

static __device__ __forceinline__ unsigned short f2bf(float x) {
    union { float f; unsigned int u; } v; v.f = x;
    unsigned int r = v.u + 0x7fffu + ((v.u >> 16) & 1u);   // RNE
    return (unsigned short)(r >> 16);
}
static __device__ __forceinline__ unsigned short f2h_bits(float x) {
    _Float16 h = (_Float16)x;
    return __builtin_bit_cast(unsigned short, h);
}
static __device__ __forceinline__ float ftanh(float x) {
    float ax = fabsf(x);
    float e  = __expf(-2.f*ax);
    float r  = (1.f - e) / (1.f + e);
    return copysignf(r, x);
}

// ---- guaranteed single-round-trip poll primitives (device scope = sc1) ----
// 64B contiguous: 4 x dwordx4 issued back-to-back, ONE s_waitcnt.
static __device__ __forceinline__ void ld64_dev(const void* p, u32x4& a, u32x4& b, u32x4& c, u32x4& d) {
    asm volatile("global_load_dwordx4 %0, %4, off sc1\n\t"
                 "global_load_dwordx4 %1, %4, off offset:16 sc1\n\t"
                 "global_load_dwordx4 %2, %4, off offset:32 sc1\n\t"
                 "global_load_dwordx4 %3, %4, off offset:48 sc1\n\t"
                 "s_waitcnt vmcnt(0)"
                 : "=&v"(a), "=&v"(b), "=&v"(c), "=&v"(d)
                 : "v"(p) : "memory");
}
// two 64B blocks (two slabs) in ONE round trip.
static __device__ __forceinline__ void ld64x2_dev(const void* p0, const void* p1,
        u32x4& a0, u32x4& b0, u32x4& c0, u32x4& d0,
        u32x4& a1, u32x4& b1, u32x4& c1, u32x4& d1) {
    asm volatile("global_load_dwordx4 %0, %8, off sc1\n\t"
                 "global_load_dwordx4 %1, %8, off offset:16 sc1\n\t"
                 "global_load_dwordx4 %2, %8, off offset:32 sc1\n\t"
                 "global_load_dwordx4 %3, %8, off offset:48 sc1\n\t"
                 "global_load_dwordx4 %4, %9, off sc1\n\t"
                 "global_load_dwordx4 %5, %9, off offset:16 sc1\n\t"
                 "global_load_dwordx4 %6, %9, off offset:32 sc1\n\t"
                 "global_load_dwordx4 %7, %9, off offset:48 sc1\n\t"
                 "s_waitcnt vmcnt(0)"
                 : "=&v"(a0), "=&v"(b0), "=&v"(c0), "=&v"(d0),
                   "=&v"(a1), "=&v"(b1), "=&v"(c1), "=&v"(d1)
                 : "v"(p0), "v"(p1) : "memory");
}
static __device__ __forceinline__ void st_dev(void* p, unsigned long long v) {
    asm volatile("global_store_dwordx2 %0, %1, off sc1" :: "v"(p), "v"(v) : "memory");
}

// ---------------------------------------------------------------------------
// prep (R1 layouts):
//  - w_ih0 -> bf16 row-major (GEMM B operand)
//  - w_hh0 -> f16 MFMA B-frags, 16-block layout [j16][kc16][wrow8][lane64][e8]
//  - w_ih1, w_hh1 -> f16 MFMA B-frags, 64-block layout [j64][kc16][nt2][lane64][e8]
//  - w1,w2 -> bf16; biases combined
// ---------------------------------------------------------------------------
__global__ void prep_kernel(const float* __restrict__ w_ih0, const float* __restrict__ w_hh0,
                            const float* __restrict__ b_ih0, const float* __restrict__ b_hh0,
                            const float* __restrict__ w_ih1, const float* __restrict__ w_hh1,
                            const float* __restrict__ b_ih1, const float* __restrict__ b_hh1,
                            const float* __restrict__ w1,   const float* __restrict__ w2,
                            unsigned short* __restrict__ w_ih0_b, _Float16* __restrict__ wfrag0,
                            _Float16* __restrict__ wfrag1x,      _Float16* __restrict__ wfrag1h,
                            unsigned short* __restrict__ w1_b,    unsigned short* __restrict__ w2_b,
                            float* __restrict__ bias0, float* __restrict__ bias1) {
    int i  = blockIdx.x * blockDim.x + threadIdx.x;
    int st = gridDim.x * blockDim.x;
    for (int k = i; k < G_*H_; k += st) w_ih0_b[k] = f2bf(w_ih0[k]);
    for (int d = i; d < G_*H_; d += st) {
        int e    = d & 7;
        int l    = (d >> 3) & 63;
        int wrow = (d >> 9) & 7;
        int kc   = (d >> 12) & 15;
        int j    = (d >> 16) & 15;
        int r    = wrow*16 + (l & 15);
        int R    = (r >> 5)*512 + j*32 + (r & 31);
        int k    = kc*32 + ((l >> 4) << 3) + e;
        wfrag0[d] = (_Float16)w_hh0[R*H_ + k];
    }
    for (int d = i; d < G_*H_; d += st) {
        int e    = d & 7;
        int l    = (d >> 3) & 63;
        int nt   = (d >> 9) & 1;
        int kc   = (d >> 10) & 15;
        int j    = (d >> 14) & 63;
        int r    = nt*16 + (l & 15);
        int R    = (r >> 3)*512 + j*8 + (r & 7);
        int k    = kc*32 + ((l >> 4) << 3) + e;
        wfrag1x[d] = (_Float16)w_ih1[R*H_ + k];
        wfrag1h[d] = (_Float16)w_hh1[R*H_ + k];
    }
    for (int k = i; k < V_*128; k += st) w2_b[k] = f2bf(w2[k]);
    for (int k = i; k < 128*H_; k += st) w1_b[k] = f2bf(w1[k]);
    for (int k = i; k < G_;     k += st) { bias0[k] = b_ih0[k] + b_hh0[k]; bias1[k] = b_ih1[k] + b_hh1[k]; }
}

// ---------------------------------------------------------------------------
__global__ void embed_kernel(const int* __restrict__ src, const float* __restrict__ w_emb,
                             const float* __restrict__ b_emb, unsigned short* __restrict__ emb) {
    int m = blockIdx.x;
    int idx = src[m];
    for (int h = threadIdx.x; h < H_; h += blockDim.x)
        emb[(long)m*H_ + h] = f2bf(w_emb[(long)h*V_ + idx] + b_emb[h]);
}

// ---------------------------------------------------------------------------
// Generic bf16 MFMA GEMM: C[M,N] = A[M,K] @ B[N,K]^T + bias[N]
// ---------------------------------------------------------------------------
template<bool RELU, bool OUT_BF16>
__launch_bounds__(256)
__global__ void gemm_kernel(const unsigned short* __restrict__ A, const unsigned short* __restrict__ Bm,
                            const float* __restrict__ bias, void* __restrict__ Cout,
                            int Ndim, int K) {
    __shared__ unsigned short At[128*40];
    __shared__ unsigned short Bt[128*40];
    int m0 = blockIdx.y * 128;
    int n0 = blockIdx.x * 128;
    int tid  = threadIdx.x;
    int lane = tid & 63, wave = tid >> 6;
    int wm = (wave >> 1) * 64, wn = (wave & 1) * 64;
    int l15 = lane & 15, l4 = lane >> 4;
    f32x4 acc[4][4] = {};

    for (int kk = 0; kk < K; kk += 32) {
        __syncthreads();
        #pragma unroll
        for (int rep = 0; rep < 2; ++rep) {
            int gid = tid + rep*256;
            int row = gid >> 2, c8 = (gid & 3) << 3;
            *(uint4*)&At[row*40 + c8] = *(const uint4*)&A[(long)(m0+row)*K + kk + c8];
            int nrow = n0 + row; if (nrow >= Ndim) nrow = Ndim - 1;
            *(uint4*)&Bt[row*40 + c8] = *(const uint4*)&Bm[(long)nrow*K + kk + c8];
        }
        __syncthreads();
        bf16x8 af[4], bfr[4];
        #pragma unroll
        for (int i = 0; i < 4; ++i)
            af[i] = *(const bf16x8*)&At[(wm + i*16 + l15)*40 + l4*8];
        #pragma unroll
        for (int j = 0; j < 4; ++j)
            bfr[j] = *(const bf16x8*)&Bt[(wn + j*16 + l15)*40 + l4*8];
        #pragma unroll
        for (int i = 0; i < 4; ++i)
            #pragma unroll
            for (int j = 0; j < 4; ++j)
                acc[i][j] = __builtin_amdgcn_mfma_f32_16x16x32_bf16(af[i], bfr[j], acc[i][j], 0, 0, 0);
    }

    #pragma unroll
    for (int i = 0; i < 4; ++i) {
        int row = m0 + wm + i*16 + l4*4;
        #pragma unroll
        for (int j = 0; j < 4; ++j) {
            int col = n0 + wn + j*16 + l15;
            if (col < Ndim) {
                float bv = bias[col];
                #pragma unroll
                for (int r = 0; r < 4; ++r) {
                    float v = acc[i][j][r] + bv;
                    if (RELU) v = v > 0.f ? v : 0.f;
                    if (OUT_BF16) ((unsigned short*)Cout)[(long)(row+r)*Ndim + col] = f2bf(v);
                    else          ((float*)Cout)[(long)(row+r)*Ndim + col] = v;
                }
            }
        }
    }
}

// ---------------------------------------------------------------------------
// Fused 2-layer wavefront-pipelined LSTM (R1 skeleton + 1-RTT poll rounds).
//  Blocks 0..15  : layer 0, block j owns h0 cols [32j,32j+32).
//  Blocks 16..79 : layer 1, block j1 owns h1 cols [8j1,8j1+8).
//  Exchange slabs are THREAD-MAJOR: logical slot sl = q*512 + r lives at
//  physical index r*8 + q, so consumer thread `tid` polls ONE contiguous
//  64B block per slab -> a single 4x dwordx4 + one s_waitcnt = 1 RTT/round.
//  Producer: sl = ch*256 + <paircol>; phys = ((sl&511)<<3)|(sl>>9).
//  Tags: hi32 = t+1 stored at step t. L0 polls slab t-1 (tag t);
//  L1 polls h0 slab t (tag t+1) + h1 slab t-1 (tag t) in one clause.
// ---------------------------------------------------------------------------
__launch_bounds__(512)
__global__ void lstm_fused_kernel(const float* __restrict__ xp,
                                  const uint4* __restrict__ wfrag0,
                                  const uint4* __restrict__ wfrag1x,
                                  const uint4* __restrict__ wfrag1h,
                                  const float* __restrict__ bias1,
                                  unsigned long long* __restrict__ h0ex,
                                  unsigned long long* __restrict__ h1ex,
                                  unsigned short* __restrict__ hout) {
    __shared__ __align__(16) char smem[156160];
    int tid  = threadIdx.x;
    int lane = tid & 63, wave = tid >> 6;
    int l15  = lane & 15, l4 = lane >> 4;

    if (blockIdx.x < 16) {
        // ================= layer 0 =================
        uint4*     w_lds = (uint4*)smem;                       // [kc16][wrow8][lane64] of 8 halves
        _Float16*  h_lds = (_Float16*)(smem + 131072);         // [16][520]
        float*     gbuf  = (float*)(smem + 131072 + 16640);    // [16][132]
        int j = blockIdx.x;
        for (int i = tid; i < 8192; i += 512) w_lds[i] = wfrag0[(long)j*8192 + i];
        for (int i = tid; i < 4160; i += 512) ((unsigned int*)h_lds)[i] = 0;
        __syncthreads();
        const _Float16* wh = (const _Float16*)w_lds;
        int ch = tid >> 5, s = tid & 31;
        int chB = tid >> 8, pr = tid & 255;   // consumer scatter ids
        float c = 0.f;
        // x-projection prefetch registers (step t held; t+1 loaded during t)
        float cxi, cxf, cxg, cxo;
        {
            const float* xr = xp + ((long)ch*S_)*G_ + j*32 + s;
            cxi = xr[0]; cxf = xr[512]; cxg = xr[1024]; cxo = xr[1536];
        }

        for (int t = 0; t < S_; ++t) {
            if (t > 0) {
                unsigned int tagv = (unsigned int)t;
                const char* pp = (const char*)(h0ex + (long)(t-1)*4096) + (long)tid*64;
                u32x4 pa, pb, pc_, pd;
                for (;;) {
                    ld64_dev(pp, pa, pb, pc_, pd);
                    bool ok = (pa.y==tagv) & (pa.w==tagv) & (pb.y==tagv) & (pb.w==tagv)
                            & (pc_.y==tagv) & (pc_.w==tagv) & (pd.y==tagv) & (pd.w==tagv);
                    if (ok) break;
                    __builtin_amdgcn_s_sleep(1);
                }
                unsigned int vals[8] = {pa.x,pa.z,pb.x,pb.z,pc_.x,pc_.z,pd.x,pd.z};
                #pragma unroll
                for (int q = 0; q < 8; ++q)
                    *(unsigned int*)&h_lds[(2*q + chB)*520 + pr*2] = vals[q];
            }
            __syncthreads();
            // prefetch next step's x-projection (used next iteration)
            float nxi=0.f, nxf=0.f, nxg=0.f, nxo=0.f;
            if (t + 1 < S_) {
                const float* xr = xp + ((long)ch*S_ + t + 1)*G_ + j*32 + s;
                nxi = xr[0]; nxf = xr[512]; nxg = xr[1024]; nxo = xr[1536];
            }
            f32x4 acc0 = {0.f,0.f,0.f,0.f}, acc1 = {0.f,0.f,0.f,0.f};
            #pragma unroll
            for (int kc = 0; kc < 8; ++kc) {
                f16x8 af = *(const f16x8*)&h_lds[l15*520 + kc*32 + l4*8];
                f16x8 bf = *(const f16x8*)&wh[(((kc*8) + wave)*64 + lane)*8];
                acc0 = __builtin_amdgcn_mfma_f32_16x16x32_f16(af, bf, acc0, 0, 0, 0);
            }
            #pragma unroll
            for (int kc = 8; kc < 16; ++kc) {
                f16x8 af = *(const f16x8*)&h_lds[l15*520 + kc*32 + l4*8];
                f16x8 bf = *(const f16x8*)&wh[(((kc*8) + wave)*64 + lane)*8];
                acc1 = __builtin_amdgcn_mfma_f32_16x16x32_f16(af, bf, acc1, 0, 0, 0);
            }
            #pragma unroll
            for (int r = 0; r < 4; ++r)
                gbuf[(l4*4 + r)*132 + wave*16 + l15] = acc0[r] + acc1[r];
            __syncthreads();
            const float* gb = gbuf + ch*132;
            float xi = cxi + gb[s], xf = cxf + gb[32+s], xg = cxg + gb[64+s], xo = cxo + gb[96+s];
            float ig = 1.f/(1.f+__expf(-xi));
            float fg = 1.f/(1.f+__expf(-xf));
            float gg = ftanh(xg);
            float og = 1.f/(1.f+__expf(-xo));
            c = fg*c + ig*gg;
            float h = og*ftanh(c);
            unsigned int me = f2h_bits(h);
            unsigned int up = (unsigned int)__shfl_down((int)me, 1, 64);
            if (!(s & 1)) {
                unsigned long long vv = ((unsigned long long)(unsigned int)(t+1) << 32)
                                      | (up << 16) | me;
                int sl = ch*256 + j*16 + (s>>1);
                int phys = ((sl & 511) << 3) | (sl >> 9);
                st_dev(&h0ex[(long)t*4096 + phys], vv);
            }
            cxi = nxi; cxf = nxf; cxg = nxg; cxo = nxo;
        }
    } else {
        // ================= layer 1 =================
        uint4*     wx   = (uint4*)smem;                        // [kc16][nt2][lane64] (x-part)
        uint4*     whh  = wx + 2048;                           // (h-part)
        _Float16*  h0l  = (_Float16*)(smem + 65536);           // [16][520]
        _Float16*  h1l  = h0l + 16*520;
        float*     gbuf = (float*)(smem + 65536 + 2*16640);    // [src2][kh2][16][36]
        float*     bl   = gbuf + 2*2*16*36;                    // [32]
        int j1 = blockIdx.x - 16;
        for (int i = tid; i < 2048; i += 512) {
            wx[i]  = wfrag1x[(long)j1*2048 + i];
            whh[i] = wfrag1h[(long)j1*2048 + i];
        }
        if (tid < 32) bl[tid] = bias1[(tid >> 3)*512 + j1*8 + (tid & 7)];
        for (int i = tid; i < 8320; i += 512) ((unsigned int*)h0l)[i] = 0;   // zero h0l+h1l
        __syncthreads();
        int ch = tid >> 3, sc = tid & 7;
        int chB = tid >> 8, pr = tid & 255;
        float c = 0.f;

        for (int t = 0; t < S_; ++t) {
            unsigned int tag0 = (unsigned int)(t+1);
            unsigned int tag1 = (unsigned int)t;
            const char* p0 = (const char*)(h0ex + (long)t*4096) + (long)tid*64;
            u32x4 a0, b0, c0, d0, a1, b1, c1, d1;
            if (t > 0) {
                const char* p1 = (const char*)(h1ex + (long)(t-1)*4096) + (long)tid*64;
                for (;;) {
                    ld64x2_dev(p0, p1, a0, b0, c0, d0, a1, b1, c1, d1);
                    bool ok = (a0.y==tag0) & (a0.w==tag0) & (b0.y==tag0) & (b0.w==tag0)
                            & (c0.y==tag0) & (c0.w==tag0) & (d0.y==tag0) & (d0.w==tag0)
                            & (a1.y==tag1) & (a1.w==tag1) & (b1.y==tag1) & (b1.w==tag1)
                            & (c1.y==tag1) & (c1.w==tag1) & (d1.y==tag1) & (d1.w==tag1);
                    if (ok) break;
                    __builtin_amdgcn_s_sleep(1);
                }
                unsigned int v1s[8] = {a1.x,a1.z,b1.x,b1.z,c1.x,c1.z,d1.x,d1.z};
                #pragma unroll
                for (int q = 0; q < 8; ++q)
                    *(unsigned int*)&h1l[(2*q + chB)*520 + pr*2] = v1s[q];
            } else {
                for (;;) {
                    ld64_dev(p0, a0, b0, c0, d0);
                    bool ok = (a0.y==tag0) & (a0.w==tag0) & (b0.y==tag0) & (b0.w==tag0)
                            & (c0.y==tag0) & (c0.w==tag0) & (d0.y==tag0) & (d0.w==tag0);
                    if (ok) break;
                    __builtin_amdgcn_s_sleep(1);
                }
            }
            unsigned int v0s[8] = {a0.x,a0.z,b0.x,b0.z,c0.x,c0.z,d0.x,d0.z};
            #pragma unroll
            for (int q = 0; q < 8; ++q)
                *(unsigned int*)&h0l[(2*q + chB)*520 + pr*2] = v0s[q];
            __syncthreads();
            {   // MFMA: wave -> (src, nt, kc-half); 8 MFMA each (split 4+4)
                int src = wave >> 2, nt = (wave >> 1) & 1, kh = wave & 1;
                const _Float16* hs = src ? h1l : h0l;
                const _Float16* ws = (const _Float16*)(src ? whh : wx);
                f32x4 acc0 = {0.f,0.f,0.f,0.f}, acc1 = {0.f,0.f,0.f,0.f};
                #pragma unroll
                for (int k2 = 0; k2 < 4; ++k2) {
                    int kc = kh*8 + k2;
                    f16x8 af = *(const f16x8*)&hs[l15*520 + kc*32 + l4*8];
                    f16x8 bf = *(const f16x8*)&ws[((kc*2 + nt)*64 + lane)*8];
                    acc0 = __builtin_amdgcn_mfma_f32_16x16x32_f16(af, bf, acc0, 0, 0, 0);
                }
                #pragma unroll
                for (int k2 = 4; k2 < 8; ++k2) {
                    int kc = kh*8 + k2;
                    f16x8 af = *(const f16x8*)&hs[l15*520 + kc*32 + l4*8];
                    f16x8 bf = *(const f16x8*)&ws[((kc*2 + nt)*64 + lane)*8];
                    acc1 = __builtin_amdgcn_mfma_f32_16x16x32_f16(af, bf, acc1, 0, 0, 0);
                }
                #pragma unroll
                for (int r = 0; r < 4; ++r)
                    gbuf[((src*2 + kh)*16 + (l4*4 + r))*36 + nt*16 + l15] = acc0[r] + acc1[r];
            }
            __syncthreads();
            if (tid < 128) {
                const float* g0 = gbuf + (0*16 + ch)*36;
                const float* g1 = gbuf + (1*16 + ch)*36;
                const float* g2 = gbuf + (2*16 + ch)*36;
                const float* g3 = gbuf + (3*16 + ch)*36;
                float xi = g0[sc]    + g1[sc]    + g2[sc]    + g3[sc]    + bl[sc];
                float xf = g0[8+sc]  + g1[8+sc]  + g2[8+sc]  + g3[8+sc]  + bl[8+sc];
                float xg = g0[16+sc] + g1[16+sc] + g2[16+sc] + g3[16+sc] + bl[16+sc];
                float xo = g0[24+sc] + g1[24+sc] + g2[24+sc] + g3[24+sc] + bl[24+sc];
                float ig = 1.f/(1.f+__expf(-xi));
                float fg = 1.f/(1.f+__expf(-xf));
                float gg = ftanh(xg);
                float og = 1.f/(1.f+__expf(-xo));
                c = fg*c + ig*gg;
                float h = og*ftanh(c);
                unsigned int me = f2h_bits(h);
                unsigned int up = (unsigned int)__shfl_down((int)me, 1, 64);
                if (!(sc & 1)) {
                    unsigned long long vv = ((unsigned long long)(unsigned int)(t+1) << 32)
                                          | (up << 16) | me;
                    int sl = ch*256 + j1*4 + (sc>>1);
                    int phys = ((sl & 511) << 3) | (sl >> 9);
                    st_dev(&h1ex[(long)t*4096 + phys], vv);
                }
                hout[((long)ch*S_ + t)*H_ + j1*8 + sc] = f2bf(h);
            }
        }
    }
}

// ---------------------------------------------------------------------------
extern "C" void kernel_launch(void* const* d_in, const int* in_sizes, int n_in,
                              void* d_out, int out_size, void* d_ws, size_t ws_size,
                              hipStream_t stream) {
    const int*   src   = (const int*)  d_in[0];
    const float* w_emb = (const float*)d_in[1];
    const float* b_emb = (const float*)d_in[2];
    const float* w_ih0 = (const float*)d_in[3];
    const float* w_hh0 = (const float*)d_in[4];
    const float* b_ih0 = (const float*)d_in[5];
    const float* b_hh0 = (const float*)d_in[6];
    const float* w_ih1 = (const float*)d_in[7];
    const float* w_hh1 = (const float*)d_in[8];
    const float* b_ih1 = (const float*)d_in[9];
    const float* b_hh1 = (const float*)d_in[10];
    const float* w1    = (const float*)d_in[11];
    const float* b1    = (const float*)d_in[12];
    const float* w2    = (const float*)d_in[13];
    const float* b2    = (const float*)d_in[14];
    float* out = (float*)d_out;

    char* ws = (char*)d_ws;
    size_t off = 0;
    auto alloc = [&](size_t bytes) -> void* {
        void* p = ws + off;
        off = (off + bytes + 255) & ~(size_t)255;
        return p;
    };
    unsigned short* w_ih0_b = (unsigned short*)alloc((size_t)G_*H_*2);
    _Float16*       wfrag0  = (_Float16*)      alloc((size_t)G_*H_*2);
    _Float16*       wfrag1x = (_Float16*)      alloc((size_t)G_*H_*2);
    _Float16*       wfrag1h = (_Float16*)      alloc((size_t)G_*H_*2);
    unsigned short* w1_b    = (unsigned short*)alloc((size_t)128*H_*2);
    unsigned short* w2_b    = (unsigned short*)alloc((size_t)V_*128*2);
    float*          bias0   = (float*)         alloc((size_t)G_*4);
    float*          bias1   = (float*)         alloc((size_t)G_*4);
    unsigned short* emb     = (unsigned short*)alloc((size_t)M_*H_*2);   // reused as hout (h1)
    unsigned short* hidb    = (unsigned short*)alloc((size_t)M_*128*2);
    float*          xp      = (float*)         alloc((size_t)M_*G_*4);
    unsigned long long* h0ex = (unsigned long long*)alloc((size_t)S_*4096*8);  // 16 MB
    unsigned long long* h1ex = (unsigned long long*)alloc((size_t)S_*4096*8);  // 16 MB

    prep_kernel<<<2048, 256, 0, stream>>>(w_ih0, w_hh0, b_ih0, b_hh0,
                                          w_ih1, w_hh1, b_ih1, b_hh1,
                                          w1, w2,
                                          w_ih0_b, wfrag0, wfrag1x, wfrag1h,
                                          w1_b, w2_b, bias0, bias1);
    embed_kernel<<<M_, 256, 0, stream>>>(src, w_emb, b_emb, emb);

    // x_proj0 = emb @ w_ih0^T + (b_ih0+b_hh0)   [8192,2048] fp32
    gemm_kernel<false,false><<<dim3(G_/128, M_/128), 256, 0, stream>>>(emb, w_ih0_b, bias0, xp, G_, H_);

    // fused 2-layer pipelined LSTM; h1 (bf16) lands in `emb` buffer (reuse)
    lstm_fused_kernel<<<80, 512, 0, stream>>>(xp, (const uint4*)wfrag0,
                                              (const uint4*)wfrag1x, (const uint4*)wfrag1h,
                                              bias1, h0ex, h1ex, emb);

    // hid = relu(h1 @ w1^T + b1)   [8192,128] bf16
    gemm_kernel<true,true><<<dim3(1, M_/128), 256, 0, stream>>>(emb, w1_b, b1, hidb, 128, H_);

    // logits = hid @ w2^T + b2     [8192,10000] fp32 -> d_out
    gemm_kernel<false,false><<<dim3((V_+127)/128, M_/128), 256, 0, stream>>>(hidb, w2_b, b2, out, V_, 128);
}

// Round 6
// 2217.625 us; speedup vs baseline: 1.3053x; 1.3053x over previous
//
#include <hip/hip_runtime.h>
#include <hip/hip_bf16.h>

#define B_ 16
#define S_ 512
#define H_ 512
#define V_ 10000
#define G_ 2048
#define M_ (B_*S_)   // 8192 tokens

typedef short bf16x8 __attribute__((ext_vector_type(8)));
typedef float f32x4 __attribute__((ext_vector_type(4)));
typedef _Float16 f16x8 __attribute__((ext_vector_type(8)));

static __device__ __forceinline__ unsigned short f2bf(float x) {
    union { float f; unsigned int u; } v; v.f = x;
    unsigned int r = v.u + 0x7fffu + ((v.u >> 16) & 1u);   // RNE
    return (unsigned short)(r >> 16);
}
static __device__ __forceinline__ unsigned short f2h_bits(float x) {
    _Float16 h = (_Float16)x;
    return __builtin_bit_cast(unsigned short, h);
}
static __device__ __forceinline__ float ftanh(float x) {
    float ax = fabsf(x);
    float e  = __expf(-2.f*ax);
    float r  = (1.f - e) / (1.f + e);
    return copysignf(r, x);
}

// ---------------------------------------------------------------------------
// prep (R1 layouts):
//  - w_ih0 -> bf16 row-major (GEMM B operand)
//  - w_hh0 -> f16 MFMA B-frags, 16-block layout [j16][kc16][wrow8][lane64][e8]
//      r = wrow*16+(l&15); R = (r>>5)*512 + j*32 + (r&31); k = kc*32+(l>>4)*8+e
//  - w_ih1, w_hh1 -> f16 MFMA B-frags, 64-block layout [j64][kc16][nt2][lane64][e8]
//      r = nt*16+(l&15) (0..31); R = (r>>3)*512 + j*8 + (r&7); same k
//  - w1,w2 -> bf16; biases combined
// ---------------------------------------------------------------------------
__global__ void prep_kernel(const float* __restrict__ w_ih0, const float* __restrict__ w_hh0,
                            const float* __restrict__ b_ih0, const float* __restrict__ b_hh0,
                            const float* __restrict__ w_ih1, const float* __restrict__ w_hh1,
                            const float* __restrict__ b_ih1, const float* __restrict__ b_hh1,
                            const float* __restrict__ w1,   const float* __restrict__ w2,
                            unsigned short* __restrict__ w_ih0_b, _Float16* __restrict__ wfrag0,
                            _Float16* __restrict__ wfrag1x,      _Float16* __restrict__ wfrag1h,
                            unsigned short* __restrict__ w1_b,    unsigned short* __restrict__ w2_b,
                            float* __restrict__ bias0, float* __restrict__ bias1) {
    int i  = blockIdx.x * blockDim.x + threadIdx.x;
    int st = gridDim.x * blockDim.x;
    for (int k = i; k < G_*H_; k += st) w_ih0_b[k] = f2bf(w_ih0[k]);
    // layer-0 recurrent frags (16-block)
    for (int d = i; d < G_*H_; d += st) {
        int e    = d & 7;
        int l    = (d >> 3) & 63;
        int wrow = (d >> 9) & 7;
        int kc   = (d >> 12) & 15;
        int j    = (d >> 16) & 15;
        int r    = wrow*16 + (l & 15);
        int R    = (r >> 5)*512 + j*32 + (r & 31);
        int k    = kc*32 + ((l >> 4) << 3) + e;
        wfrag0[d] = (_Float16)w_hh0[R*H_ + k];
    }
    // layer-1 frags (64-block): both x-part (w_ih1) and h-part (w_hh1)
    for (int d = i; d < G_*H_; d += st) {
        int e    = d & 7;
        int l    = (d >> 3) & 63;
        int nt   = (d >> 9) & 1;
        int kc   = (d >> 10) & 15;
        int j    = (d >> 14) & 63;
        int r    = nt*16 + (l & 15);
        int R    = (r >> 3)*512 + j*8 + (r & 7);
        int k    = kc*32 + ((l >> 4) << 3) + e;
        wfrag1x[d] = (_Float16)w_ih1[R*H_ + k];
        wfrag1h[d] = (_Float16)w_hh1[R*H_ + k];
    }
    for (int k = i; k < V_*128; k += st) w2_b[k] = f2bf(w2[k]);
    for (int k = i; k < 128*H_; k += st) w1_b[k] = f2bf(w1[k]);
    for (int k = i; k < G_;     k += st) { bias0[k] = b_ih0[k] + b_hh0[k]; bias1[k] = b_ih1[k] + b_hh1[k]; }
}

// ---------------------------------------------------------------------------
__global__ void embed_kernel(const int* __restrict__ src, const float* __restrict__ w_emb,
                             const float* __restrict__ b_emb, unsigned short* __restrict__ emb) {
    int m = blockIdx.x;
    int idx = src[m];
    for (int h = threadIdx.x; h < H_; h += blockDim.x)
        emb[(long)m*H_ + h] = f2bf(w_emb[(long)h*V_ + idx] + b_emb[h]);
}

// ---------------------------------------------------------------------------
// Generic bf16 MFMA GEMM: C[M,N] = A[M,K] @ B[N,K]^T + bias[N]
// ---------------------------------------------------------------------------
template<bool RELU, bool OUT_BF16>
__launch_bounds__(256)
__global__ void gemm_kernel(const unsigned short* __restrict__ A, const unsigned short* __restrict__ Bm,
                            const float* __restrict__ bias, void* __restrict__ Cout,
                            int Ndim, int K) {
    __shared__ unsigned short At[128*40];
    __shared__ unsigned short Bt[128*40];
    int m0 = blockIdx.y * 128;
    int n0 = blockIdx.x * 128;
    int tid  = threadIdx.x;
    int lane = tid & 63, wave = tid >> 6;
    int wm = (wave >> 1) * 64, wn = (wave & 1) * 64;
    int l15 = lane & 15, l4 = lane >> 4;
    f32x4 acc[4][4] = {};

    for (int kk = 0; kk < K; kk += 32) {
        __syncthreads();
        #pragma unroll
        for (int rep = 0; rep < 2; ++rep) {
            int gid = tid + rep*256;
            int row = gid >> 2, c8 = (gid & 3) << 3;
            *(uint4*)&At[row*40 + c8] = *(const uint4*)&A[(long)(m0+row)*K + kk + c8];
            int nrow = n0 + row; if (nrow >= Ndim) nrow = Ndim - 1;
            *(uint4*)&Bt[row*40 + c8] = *(const uint4*)&Bm[(long)nrow*K + kk + c8];
        }
        __syncthreads();
        bf16x8 af[4], bfr[4];
        #pragma unroll
        for (int i = 0; i < 4; ++i)
            af[i] = *(const bf16x8*)&At[(wm + i*16 + l15)*40 + l4*8];
        #pragma unroll
        for (int j = 0; j < 4; ++j)
            bfr[j] = *(const bf16x8*)&Bt[(wn + j*16 + l15)*40 + l4*8];
        #pragma unroll
        for (int i = 0; i < 4; ++i)
            #pragma unroll
            for (int j = 0; j < 4; ++j)
                acc[i][j] = __builtin_amdgcn_mfma_f32_16x16x32_bf16(af[i], bfr[j], acc[i][j], 0, 0, 0);
    }

    #pragma unroll
    for (int i = 0; i < 4; ++i) {
        int row = m0 + wm + i*16 + l4*4;
        #pragma unroll
        for (int j = 0; j < 4; ++j) {
            int col = n0 + wn + j*16 + l15;
            if (col < Ndim) {
                float bv = bias[col];
                #pragma unroll
                for (int r = 0; r < 4; ++r) {
                    float v = acc[i][j][r] + bv;
                    if (RELU) v = v > 0.f ? v : 0.f;
                    if (OUT_BF16) ((unsigned short*)Cout)[(long)(row+r)*Ndim + col] = f2bf(v);
                    else          ((float*)Cout)[(long)(row+r)*Ndim + col] = v;
                }
            }
        }
    }
}

// ---------------------------------------------------------------------------
// Fused 2-layer wavefront-pipelined LSTM (R1 skeleton + LIGHT-PROBE polling).
//  Blocks 0..15  : layer 0, block j owns h0 cols [32j,32j+32) (128 gate rows).
//  Blocks 16..79 : layer 1, block j1 owns h1 cols [8j1,8j1+8) (32 gate rows).
//  Exchange: tagged u64 (hi32 = t+1, lo32 = two f16), t-indexed slabs.
//  Poll protocol: each thread's 8 slots all come from ONE producer block
//  (L0: j=(tid>>4)&15; L1: j1=(tid>>2)&63). So: spin on ONE 8B slot (q=0)
//  with s_sleep(2) backoff -> ~8-16x less coherence-point traffic than
//  full-payload rounds (the R1-R5 bottleneck theory: fabric congestion).
//  On probe hit, bulk-read all slots once; verify-all loop retained for
//  correctness (relaxed stores are unordered; rarely spins an extra round).
// ---------------------------------------------------------------------------
__launch_bounds__(512)
__global__ void lstm_fused_kernel(const float* __restrict__ xp,
                                  const uint4* __restrict__ wfrag0,
                                  const uint4* __restrict__ wfrag1x,
                                  const uint4* __restrict__ wfrag1h,
                                  const float* __restrict__ bias1,
                                  unsigned long long* __restrict__ h0ex,
                                  unsigned long long* __restrict__ h1ex,
                                  unsigned short* __restrict__ hout) {
    __shared__ __align__(16) char smem[156160];
    int tid  = threadIdx.x;
    int lane = tid & 63, wave = tid >> 6;
    int l15  = lane & 15, l4 = lane >> 4;

    if (blockIdx.x < 16) {
        // ================= layer 0 =================
        uint4*     w_lds = (uint4*)smem;                       // [kc16][wrow8][lane64] of 8 halves
        _Float16*  h_lds = (_Float16*)(smem + 131072);         // [16][520]
        float*     gbuf  = (float*)(smem + 131072 + 16640);    // [16][132]
        int j = blockIdx.x;
        for (int i = tid; i < 8192; i += 512) w_lds[i] = wfrag0[(long)j*8192 + i];
        for (int i = tid; i < 4160; i += 512) ((unsigned int*)h_lds)[i] = 0;
        __syncthreads();
        const _Float16* wh = (const _Float16*)w_lds;
        int ch = tid >> 5, s = tid & 31;    // elementwise: chain, col-in-slice
        float c = 0.f;

        for (int t = 0; t < S_; ++t) {
            const float* xr = xp + ((long)ch*S_ + t)*G_ + j*32 + s;   // hoisted loads
            float xi = xr[0], xf = xr[512], xg = xr[1024], xo = xr[1536];
            if (t > 0) {
                unsigned int tagv = (unsigned int)t;
                const unsigned long long* base = h0ex + (long)(t-1)*4096;
                // --- light probe: ONE 8B slot, s_sleep(2) backoff ---
                unsigned long long v[8];
                v[0] = __hip_atomic_load(base + tid, __ATOMIC_RELAXED, __HIP_MEMORY_SCOPE_AGENT);
                while ((unsigned int)(v[0] >> 32) != tagv) {
                    __builtin_amdgcn_s_sleep(2);
                    v[0] = __hip_atomic_load(base + tid, __ATOMIC_RELAXED, __HIP_MEMORY_SCOPE_AGENT);
                }
                // --- bulk read + verify-all (rarely loops) ---
                for (;;) {
                    #pragma unroll
                    for (int q = 1; q < 8; ++q)
                        v[q] = __hip_atomic_load(base + q*512 + tid, __ATOMIC_RELAXED, __HIP_MEMORY_SCOPE_AGENT);
                    bool ok = true;
                    #pragma unroll
                    for (int q = 1; q < 8; ++q)
                        ok &= ((unsigned int)(v[q] >> 32) == tagv);
                    if (ok) break;
                    __builtin_amdgcn_s_sleep(1);
                }
                #pragma unroll
                for (int q = 0; q < 8; ++q) {
                    int w = q*512 + tid;
                    *(unsigned int*)&h_lds[(w >> 8)*520 + (w & 255)*2] = (unsigned int)v[q];
                }
            }
            __syncthreads();
            f32x4 acc0 = {0.f,0.f,0.f,0.f}, acc1 = {0.f,0.f,0.f,0.f};
            #pragma unroll
            for (int kc = 0; kc < 8; ++kc) {
                f16x8 af = *(const f16x8*)&h_lds[l15*520 + kc*32 + l4*8];
                f16x8 bf = *(const f16x8*)&wh[(((kc*8) + wave)*64 + lane)*8];
                acc0 = __builtin_amdgcn_mfma_f32_16x16x32_f16(af, bf, acc0, 0, 0, 0);
            }
            #pragma unroll
            for (int kc = 8; kc < 16; ++kc) {
                f16x8 af = *(const f16x8*)&h_lds[l15*520 + kc*32 + l4*8];
                f16x8 bf = *(const f16x8*)&wh[(((kc*8) + wave)*64 + lane)*8];
                acc1 = __builtin_amdgcn_mfma_f32_16x16x32_f16(af, bf, acc1, 0, 0, 0);
            }
            #pragma unroll
            for (int r = 0; r < 4; ++r)
                gbuf[(l4*4 + r)*132 + wave*16 + l15] = acc0[r] + acc1[r];
            __syncthreads();
            const float* gb = gbuf + ch*132;
            xi += gb[s]; xf += gb[32+s]; xg += gb[64+s]; xo += gb[96+s];
            float ig = 1.f/(1.f+__expf(-xi));
            float fg = 1.f/(1.f+__expf(-xf));
            float gg = ftanh(xg);
            float og = 1.f/(1.f+__expf(-xo));
            c = fg*c + ig*gg;
            float h = og*ftanh(c);
            unsigned int me = f2h_bits(h);
            unsigned int up = (unsigned int)__shfl_down((int)me, 1, 64);
            if (!(s & 1)) {
                unsigned long long vv = ((unsigned long long)(unsigned int)(t+1) << 32)
                                      | (up << 16) | me;
                __hip_atomic_store(&h0ex[(long)t*4096 + ch*256 + j*16 + (s>>1)], vv,
                                   __ATOMIC_RELAXED, __HIP_MEMORY_SCOPE_AGENT);
            }
        }
    } else {
        // ================= layer 1 =================
        uint4*     wx   = (uint4*)smem;                        // [kc16][nt2][lane64] (x-part)
        uint4*     whh  = wx + 2048;                           // (h-part)
        _Float16*  h0l  = (_Float16*)(smem + 65536);           // [16][520]
        _Float16*  h1l  = h0l + 16*520;
        float*     gbuf = (float*)(smem + 65536 + 2*16640);    // [src2][kh2][16][36]
        float*     bl   = gbuf + 2*2*16*36;                    // [32]
        int j1 = blockIdx.x - 16;
        for (int i = tid; i < 2048; i += 512) {
            wx[i]  = wfrag1x[(long)j1*2048 + i];
            whh[i] = wfrag1h[(long)j1*2048 + i];
        }
        if (tid < 32) bl[tid] = bias1[(tid >> 3)*512 + j1*8 + (tid & 7)];
        for (int i = tid; i < 8320; i += 512) ((unsigned int*)h0l)[i] = 0;   // zero h0l+h1l
        __syncthreads();
        int ch = tid >> 3, sc = tid & 7;    // elementwise ids (tid<128)
        float c = 0.f;

        for (int t = 0; t < S_; ++t) {
            {   // poll h0 slab t (tag t+1) and h1 slab t-1 (tag t)
                unsigned int tag0 = (unsigned int)(t+1);
                unsigned int tag1 = (unsigned int)t;
                const unsigned long long* b0 = h0ex + (long)t*4096;
                const unsigned long long* b1 = h1ex + (long)(t > 0 ? t-1 : 0)*4096;
                unsigned long long v0[8], v1[8];
                // --- light probe: one 8B slot per slab ---
                v0[0] = __hip_atomic_load(b0 + tid, __ATOMIC_RELAXED, __HIP_MEMORY_SCOPE_AGENT);
                v1[0] = (t > 0) ? __hip_atomic_load(b1 + tid, __ATOMIC_RELAXED, __HIP_MEMORY_SCOPE_AGENT)
                                : ((unsigned long long)tag1 << 32);
                while (((unsigned int)(v0[0] >> 32) != tag0) | ((unsigned int)(v1[0] >> 32) != tag1)) {
                    __builtin_amdgcn_s_sleep(2);
                    v0[0] = __hip_atomic_load(b0 + tid, __ATOMIC_RELAXED, __HIP_MEMORY_SCOPE_AGENT);
                    if (t > 0)
                        v1[0] = __hip_atomic_load(b1 + tid, __ATOMIC_RELAXED, __HIP_MEMORY_SCOPE_AGENT);
                }
                // --- bulk read + verify-all (rarely loops) ---
                for (;;) {
                    #pragma unroll
                    for (int q = 1; q < 8; ++q)
                        v0[q] = __hip_atomic_load(b0 + q*512 + tid, __ATOMIC_RELAXED, __HIP_MEMORY_SCOPE_AGENT);
                    if (t > 0) {
                        #pragma unroll
                        for (int q = 1; q < 8; ++q)
                            v1[q] = __hip_atomic_load(b1 + q*512 + tid, __ATOMIC_RELAXED, __HIP_MEMORY_SCOPE_AGENT);
                    }
                    bool ok = true;
                    #pragma unroll
                    for (int q = 1; q < 8; ++q)
                        ok &= ((unsigned int)(v0[q] >> 32) == tag0);
                    if (t > 0) {
                        #pragma unroll
                        for (int q = 1; q < 8; ++q)
                            ok &= ((unsigned int)(v1[q] >> 32) == tag1);
                    }
                    if (ok) break;
                    __builtin_amdgcn_s_sleep(1);
                }
                if (t > 0) {
                    #pragma unroll
                    for (int q = 0; q < 8; ++q) {
                        int w = q*512 + tid;
                        *(unsigned int*)&h1l[(w >> 8)*520 + (w & 255)*2] = (unsigned int)v1[q];
                    }
                }
                #pragma unroll
                for (int q = 0; q < 8; ++q) {
                    int w = q*512 + tid;
                    *(unsigned int*)&h0l[(w >> 8)*520 + (w & 255)*2] = (unsigned int)v0[q];
                }
            }
            __syncthreads();
            {   // MFMA: wave -> (src, nt, kc-half); 8 MFMA each (split 4+4)
                int src = wave >> 2, nt = (wave >> 1) & 1, kh = wave & 1;
                const _Float16* hs = src ? h1l : h0l;
                const _Float16* ws = (const _Float16*)(src ? whh : wx);
                f32x4 acc0 = {0.f,0.f,0.f,0.f}, acc1 = {0.f,0.f,0.f,0.f};
                #pragma unroll
                for (int k2 = 0; k2 < 4; ++k2) {
                    int kc = kh*8 + k2;
                    f16x8 af = *(const f16x8*)&hs[l15*520 + kc*32 + l4*8];
                    f16x8 bf = *(const f16x8*)&ws[((kc*2 + nt)*64 + lane)*8];
                    acc0 = __builtin_amdgcn_mfma_f32_16x16x32_f16(af, bf, acc0, 0, 0, 0);
                }
                #pragma unroll
                for (int k2 = 4; k2 < 8; ++k2) {
                    int kc = kh*8 + k2;
                    f16x8 af = *(const f16x8*)&hs[l15*520 + kc*32 + l4*8];
                    f16x8 bf = *(const f16x8*)&ws[((kc*2 + nt)*64 + lane)*8];
                    acc1 = __builtin_amdgcn_mfma_f32_16x16x32_f16(af, bf, acc1, 0, 0, 0);
                }
                #pragma unroll
                for (int r = 0; r < 4; ++r)
                    gbuf[((src*2 + kh)*16 + (l4*4 + r))*36 + nt*16 + l15] = acc0[r] + acc1[r];
            }
            __syncthreads();
            if (tid < 128) {
                const float* g0 = gbuf + (0*16 + ch)*36;
                const float* g1 = gbuf + (1*16 + ch)*36;
                const float* g2 = gbuf + (2*16 + ch)*36;
                const float* g3 = gbuf + (3*16 + ch)*36;
                float xi = g0[sc]    + g1[sc]    + g2[sc]    + g3[sc]    + bl[sc];
                float xf = g0[8+sc]  + g1[8+sc]  + g2[8+sc]  + g3[8+sc]  + bl[8+sc];
                float xg = g0[16+sc] + g1[16+sc] + g2[16+sc] + g3[16+sc] + bl[16+sc];
                float xo = g0[24+sc] + g1[24+sc] + g2[24+sc] + g3[24+sc] + bl[24+sc];
                float ig = 1.f/(1.f+__expf(-xi));
                float fg = 1.f/(1.f+__expf(-xf));
                float gg = ftanh(xg);
                float og = 1.f/(1.f+__expf(-xo));
                c = fg*c + ig*gg;
                float h = og*ftanh(c);
                hout[((long)ch*S_ + t)*H_ + j1*8 + sc] = f2bf(h);
                unsigned int me = f2h_bits(h);
                unsigned int up = (unsigned int)__shfl_down((int)me, 1, 64);
                if (!(sc & 1)) {
                    unsigned long long vv = ((unsigned long long)(unsigned int)(t+1) << 32)
                                          | (up << 16) | me;
                    __hip_atomic_store(&h1ex[(long)t*4096 + ch*256 + j1*4 + (sc>>1)], vv,
                                       __ATOMIC_RELAXED, __HIP_MEMORY_SCOPE_AGENT);
                }
            }
        }
    }
}

// ---------------------------------------------------------------------------
extern "C" void kernel_launch(void* const* d_in, const int* in_sizes, int n_in,
                              void* d_out, int out_size, void* d_ws, size_t ws_size,
                              hipStream_t stream) {
    const int*   src   = (const int*)  d_in[0];
    const float* w_emb = (const float*)d_in[1];
    const float* b_emb = (const float*)d_in[2];
    const float* w_ih0 = (const float*)d_in[3];
    const float* w_hh0 = (const float*)d_in[4];
    const float* b_ih0 = (const float*)d_in[5];
    const float* b_hh0 = (const float*)d_in[6];
    const float* w_ih1 = (const float*)d_in[7];
    const float* w_hh1 = (const float*)d_in[8];
    const float* b_ih1 = (const float*)d_in[9];
    const float* b_hh1 = (const float*)d_in[10];
    const float* w1    = (const float*)d_in[11];
    const float* b1    = (const float*)d_in[12];
    const float* w2    = (const float*)d_in[13];
    const float* b2    = (const float*)d_in[14];
    float* out = (float*)d_out;

    char* ws = (char*)d_ws;
    size_t off = 0;
    auto alloc = [&](size_t bytes) -> void* {
        void* p = ws + off;
        off = (off + bytes + 255) & ~(size_t)255;
        return p;
    };
    unsigned short* w_ih0_b = (unsigned short*)alloc((size_t)G_*H_*2);
    _Float16*       wfrag0  = (_Float16*)      alloc((size_t)G_*H_*2);
    _Float16*       wfrag1x = (_Float16*)      alloc((size_t)G_*H_*2);
    _Float16*       wfrag1h = (_Float16*)      alloc((size_t)G_*H_*2);
    unsigned short* w1_b    = (unsigned short*)alloc((size_t)128*H_*2);
    unsigned short* w2_b    = (unsigned short*)alloc((size_t)V_*128*2);
    float*          bias0   = (float*)         alloc((size_t)G_*4);
    float*          bias1   = (float*)         alloc((size_t)G_*4);
    unsigned short* emb     = (unsigned short*)alloc((size_t)M_*H_*2);   // reused as hout (h1)
    unsigned short* hidb    = (unsigned short*)alloc((size_t)M_*128*2);
    float*          xp      = (float*)         alloc((size_t)M_*G_*4);
    unsigned long long* h0ex = (unsigned long long*)alloc((size_t)S_*4096*8);  // 16 MB
    unsigned long long* h1ex = (unsigned long long*)alloc((size_t)S_*4096*8);  // 16 MB

    prep_kernel<<<2048, 256, 0, stream>>>(w_ih0, w_hh0, b_ih0, b_hh0,
                                          w_ih1, w_hh1, b_ih1, b_hh1,
                                          w1, w2,
                                          w_ih0_b, wfrag0, wfrag1x, wfrag1h,
                                          w1_b, w2_b, bias0, bias1);
    embed_kernel<<<M_, 256, 0, stream>>>(src, w_emb, b_emb, emb);

    // x_proj0 = emb @ w_ih0^T + (b_ih0+b_hh0)   [8192,2048] fp32
    gemm_kernel<false,false><<<dim3(G_/128, M_/128), 256, 0, stream>>>(emb, w_ih0_b, bias0, xp, G_, H_);

    // fused 2-layer pipelined LSTM; h1 (bf16) lands in `emb` buffer (reuse)
    lstm_fused_kernel<<<80, 512, 0, stream>>>(xp, (const uint4*)wfrag0,
                                              (const uint4*)wfrag1x, (const uint4*)wfrag1h,
                                              bias1, h0ex, h1ex, emb);

    // hid = relu(h1 @ w1^T + b1)   [8192,128] bf16
    gemm_kernel<true,true><<<dim3(1, M_/128), 256, 0, stream>>>(emb, w1_b, b1, hidb, 128, H_);

    // logits = hid @ w2^T + b2     [8192,10000] fp32 -> d_out
    gemm_kernel<false,false><<<dim3((V_+127)/128, M_/128), 256, 0, stream>>>(hidb, w2_b, b2, out, V_, 128);
}